// Round 1
// baseline (940.643 us; speedup 1.0000x reference)
//
#include <hip/hip_runtime.h>
#include <cstdint>
#include <cstddef>

#define N_TOK 8192
#define DIM   1024
#define HID   4096
#define DOUT  1024
#define NEXP  8

typedef short  s16x8 __attribute__((ext_vector_type(8)));
typedef __bf16 b16x8 __attribute__((ext_vector_type(8)));
typedef float  f32x4 __attribute__((ext_vector_type(4)));

__device__ __forceinline__ unsigned short f2bf(float f) {
  unsigned u = __float_as_uint(f);
  u += 0x7fffu + ((u >> 16) & 1u);
  return (unsigned short)(u >> 16);
}

__device__ __forceinline__ float gelu_f(float v) {
  return 0.5f * v * (1.0f + erff(v * 0.70710678118654752440f));
}

// async global->LDS, 16B per lane. LDS dest must be wave-uniform base; HW
// writes lane i at base + i*16. Global src is per-lane.
__device__ __forceinline__ void gl_lds16(const void* g, void* l) {
  auto gp = (__attribute__((address_space(1))) void*)(reinterpret_cast<uintptr_t>(g));
  auto lp = (__attribute__((address_space(3))) void*)(reinterpret_cast<uintptr_t>(l));
  __builtin_amdgcn_global_load_lds(gp, lp, 16, 0, 0);
}

// ---------------- small kernels ----------------

__global__ void init_kernel(int* counts) {
  if (threadIdx.x < NEXP) counts[threadIdx.x] = 0;
}

__global__ void cast_x_kernel(const float* __restrict__ src,
                              unsigned short* __restrict__ dst) {
  int i = blockIdx.x * 256 + threadIdx.x;
  float4 v = reinterpret_cast<const float4*>(src)[i];
  ushort4 o;
  o.x = f2bf(v.x); o.y = f2bf(v.y); o.z = f2bf(v.z); o.w = f2bf(v.w);
  reinterpret_cast<ushort4*>(dst)[i] = o;
}

// src [R][C] f32 (batched by blockIdx.z) -> dst [C][R] bf16
__global__ void transpose_cast_kernel(const float* __restrict__ src,
                                      unsigned short* __restrict__ dst,
                                      int R, int C) {
  __shared__ float tile[32][33];
  size_t base = (size_t)blockIdx.z * (size_t)R * (size_t)C;
  src += base; dst += base;
  int c0 = blockIdx.x * 32, r0 = blockIdx.y * 32;
  int tx = threadIdx.x, ty = threadIdx.y;  // 32 x 8
#pragma unroll
  for (int i = 0; i < 4; ++i)
    tile[ty + 8 * i][tx] = src[(size_t)(r0 + ty + 8 * i) * C + (c0 + tx)];
  __syncthreads();
#pragma unroll
  for (int i = 0; i < 4; ++i)
    dst[(size_t)(c0 + ty + 8 * i) * R + (r0 + tx)] = f2bf(tile[tx][ty + 8 * i]);
}

// one wave per token: f32 gate logits, top-2, renormalized weights
__global__ void gate_kernel(const float* __restrict__ x,
                            const float* __restrict__ gw,
                            int* __restrict__ topk_e,
                            float* __restrict__ topk_w,
                            int* __restrict__ counts) {
  int w = threadIdx.x >> 6, lane = threadIdx.x & 63;
  int t = blockIdx.x * 4 + w;
  const float* xr = x + (size_t)t * DIM;
  float acc[8];
#pragma unroll
  for (int e = 0; e < 8; ++e) acc[e] = 0.f;
  for (int i = 0; i < DIM / 64; ++i) {
    int d = lane + (i << 6);
    float xv = xr[d];
    float4 g0 = *reinterpret_cast<const float4*>(gw + (size_t)d * 8);
    float4 g1 = *reinterpret_cast<const float4*>(gw + (size_t)d * 8 + 4);
    acc[0] += xv * g0.x; acc[1] += xv * g0.y; acc[2] += xv * g0.z; acc[3] += xv * g0.w;
    acc[4] += xv * g1.x; acc[5] += xv * g1.y; acc[6] += xv * g1.z; acc[7] += xv * g1.w;
  }
#pragma unroll
  for (int o = 32; o; o >>= 1)
#pragma unroll
    for (int e = 0; e < 8; ++e) acc[e] += __shfl_down(acc[e], o);
  if (lane == 0) {
    int e0 = 0;
#pragma unroll
    for (int e = 1; e < 8; ++e) if (acc[e] > acc[e0]) e0 = e;
    int e1 = -1;
#pragma unroll
    for (int e = 0; e < 8; ++e) {
      if (e == e0) continue;
      if (e1 < 0 || acc[e] > acc[e1]) e1 = e;
    }
    float w0 = 1.0f / (1.0f + expf(acc[e1] - acc[e0]));  // == p0/(p0+p1)
    topk_e[t * 2 + 0] = e0;
    topk_e[t * 2 + 1] = e1;
    topk_w[t * 2 + 0] = w0;
    topk_w[t * 2 + 1] = 1.0f - w0;
    atomicAdd(&counts[e0], 1);
    atomicAdd(&counts[e1], 1);
  }
}

__global__ void offsets_kernel(const int* __restrict__ counts,
                               int* __restrict__ offsets,
                               int* __restrict__ cursor) {
  if (threadIdx.x == 0) {
    int o = 0;
    for (int e = 0; e < NEXP; ++e) {
      offsets[e] = o; cursor[e] = o; o += counts[e];
    }
    offsets[NEXP] = o;
  }
}

__global__ void scatter_kernel(const int* __restrict__ topk_e,
                               int* __restrict__ cursor,
                               int* __restrict__ rowmap) {
  int t = blockIdx.x * 256 + threadIdx.x;
#pragma unroll
  for (int s = 0; s < 2; ++s) {
    int e = topk_e[t * 2 + s];
    int p = atomicAdd(&cursor[e], 1);
    rowmap[p] = t * 2 + s;
  }
}

// ---------------- MFMA GEMM ----------------
// C[M x Ncols] = A[. x K] (K-contig rows) * Bt[Ncols x K] (K-contig rows)
// MODE 0: expert GEMM1, gathered A rows via rowmap, epi: gelu(acc+b1)->bf16 h
// MODE 1: expert GEMM2, A rows compact (h), epi: atomicAdd(accb, w*(acc+b2))
// MODE 2: shared GEMM, dense, epi: accb = 0.5*gelu(acc+b)
template <int MODE>
__global__ __launch_bounds__(256, 2) void gemm_mfma(
    const unsigned short* __restrict__ A,
    const unsigned short* __restrict__ Ball,
    const float* __restrict__ biasAll,
    unsigned short* __restrict__ hOut,
    float* __restrict__ accb,
    const int* __restrict__ rowmap,
    const int* __restrict__ offsets,
    const float* __restrict__ topkw,
    int K, int Ncols, int M2, int MT, int NT) {
  int bid = blockIdx.x;
  int e, mt, nt, rowBase, cnt;
  if (MODE == 2) {
    e = 0; mt = bid / NT; nt = bid % NT; rowBase = 0; cnt = M2;
  } else {
    int per = MT * NT;
    e = bid / per;
    int r = bid % per;
    mt = r / NT; nt = r % NT;
    rowBase = offsets[e];
    cnt = offsets[e + 1] - rowBase;
    if (mt * 128 >= cnt) return;
  }
  const unsigned short* B = Ball + (size_t)e * Ncols * K;
  const float* bias = biasAll + (size_t)e * Ncols;

  int tid = threadIdx.x;
  int w = tid >> 6, lane = tid & 63;
  int wm = w >> 1, wn = w & 1;

  __shared__ __attribute__((aligned(16))) unsigned short As[2][128][32];
  __shared__ __attribute__((aligned(16))) unsigned short Bs[2][128][32];

  // staging geometry: per round, wave w loads tile rows [w*16, w*16+16),
  // lane covers row w*16 + (lane>>2), bytes (lane&3)*16 of the 64B row slice.
  int li = (w << 4) + (lane >> 2);
  int kb = (lane & 3) * 8;  // element offset

  const unsigned short* asrc[2];
#pragma unroll
  for (int rnd = 0; rnd < 2; ++rnd) {
    int i = li + rnd * 64;
    int r = mt * 128 + i;
    size_t arow;
    if (MODE == 0) {
      int rr = r < cnt ? r : cnt - 1;
      arow = (size_t)(rowmap[rowBase + rr] >> 1);
    } else if (MODE == 1) {
      int rr = r < cnt ? r : cnt - 1;
      arow = (size_t)(rowBase + rr);
    } else {
      arow = (size_t)r;
    }
    asrc[rnd] = A + arow * (size_t)K + kb;
  }
  const unsigned short* bsrc[2];
  bsrc[0] = B + (size_t)(nt * 128 + li) * K + kb;
  bsrc[1] = bsrc[0] + (size_t)64 * K;

  f32x4 acc[4][4] = {};
  int ldsrow = (w << 4);

  auto stage = [&](int buf, int kt) {
    int ko = kt * 32;
    gl_lds16(asrc[0] + ko, &As[buf][ldsrow][0]);
    gl_lds16(asrc[1] + ko, &As[buf][ldsrow + 64][0]);
    gl_lds16(bsrc[0] + ko, &Bs[buf][ldsrow][0]);
    gl_lds16(bsrc[1] + ko, &Bs[buf][ldsrow + 64][0]);
  };

  stage(0, 0);
  __syncthreads();

  int KT = K >> 5;
  int fr = lane & 15, fg = lane >> 4;
  for (int kt = 0; kt < KT; ++kt) {
    int cur = kt & 1;
    if (kt + 1 < KT) stage(cur ^ 1, kt + 1);
    s16x8 af[4], bf[4];
#pragma unroll
    for (int m = 0; m < 4; ++m)
      af[m] = *reinterpret_cast<const s16x8*>(&As[cur][wm * 64 + m * 16 + fr][fg * 8]);
#pragma unroll
    for (int n = 0; n < 4; ++n)
      bf[n] = *reinterpret_cast<const s16x8*>(&Bs[cur][wn * 64 + n * 16 + fr][fg * 8]);
#pragma unroll
    for (int m = 0; m < 4; ++m)
#pragma unroll
      for (int n = 0; n < 4; ++n)
        acc[m][n] = __builtin_amdgcn_mfma_f32_16x16x32_bf16(
            __builtin_bit_cast(b16x8, af[m]), __builtin_bit_cast(b16x8, bf[n]),
            acc[m][n], 0, 0, 0);
    __syncthreads();
  }

  // epilogue: C[row][col], col = lane&15 within frag, row = (lane>>4)*4 + q
#pragma unroll
  for (int m = 0; m < 4; ++m) {
#pragma unroll
    for (int q = 0; q < 4; ++q) {
      int rloc = wm * 64 + m * 16 + fg * 4 + q;
      int r = mt * 128 + rloc;
      if (MODE != 2 && r >= cnt) continue;
      if (MODE == 0) {
        size_t orow = (size_t)(rowBase + r) * Ncols;
#pragma unroll
        for (int n = 0; n < 4; ++n) {
          int col = nt * 128 + wn * 64 + n * 16 + fr;
          float v = acc[m][n][q] + bias[col];
          hOut[orow + col] = f2bf(gelu_f(v));
        }
      } else if (MODE == 1) {
        int rm = rowmap[rowBase + r];
        int token = rm >> 1;
        float wgt = topkw[rm];
        float* orow = accb + (size_t)token * Ncols;
#pragma unroll
        for (int n = 0; n < 4; ++n) {
          int col = nt * 128 + wn * 64 + n * 16 + fr;
          atomicAdd(&orow[col], wgt * (acc[m][n][q] + bias[col]));
        }
      } else {
        float* orow = accb + (size_t)r * Ncols;
#pragma unroll
        for (int n = 0; n < 4; ++n) {
          int col = nt * 128 + wn * 64 + n * 16 + fr;
          orow[col] = 0.5f * gelu_f(acc[m][n][q] + bias[col]);
        }
      }
    }
  }
}

// ---------------- LayerNorm ----------------
__global__ void ln_kernel(const float* __restrict__ acc,
                          const float* __restrict__ gamma,
                          const float* __restrict__ beta,
                          float* __restrict__ out) {
  int t = blockIdx.x, tid = threadIdx.x;
  const float4* row = reinterpret_cast<const float4*>(acc + (size_t)t * DOUT);
  float4 v = row[tid];
  float s = v.x + v.y + v.z + v.w;
  float q = v.x * v.x + v.y * v.y + v.z * v.z + v.w * v.w;
#pragma unroll
  for (int o = 32; o; o >>= 1) {
    s += __shfl_down(s, o);
    q += __shfl_down(q, o);
  }
  __shared__ float ss[4], sq[4];
  int w = tid >> 6, lane = tid & 63;
  if (lane == 0) { ss[w] = s; sq[w] = q; }
  __syncthreads();
  float S = ss[0] + ss[1] + ss[2] + ss[3];
  float Q = sq[0] + sq[1] + sq[2] + sq[3];
  float mean = S * (1.0f / DOUT);
  float var = Q * (1.0f / DOUT) - mean * mean;
  float inv = rsqrtf(var + 1e-5f);
  float4 g = reinterpret_cast<const float4*>(gamma)[tid];
  float4 b = reinterpret_cast<const float4*>(beta)[tid];
  float4 o;
  o.x = (v.x - mean) * inv * g.x + b.x;
  o.y = (v.y - mean) * inv * g.y + b.y;
  o.z = (v.z - mean) * inv * g.z + b.z;
  o.w = (v.w - mean) * inv * g.w + b.w;
  reinterpret_cast<float4*>(out + (size_t)t * DOUT)[tid] = o;
}

// ---------------- host ----------------
extern "C" void kernel_launch(void* const* d_in, const int* in_sizes, int n_in,
                              void* d_out, int out_size, void* d_ws, size_t ws_size,
                              hipStream_t stream) {
  const float* x       = (const float*)d_in[0];
  const float* W1      = (const float*)d_in[1];
  const float* b1      = (const float*)d_in[2];
  const float* W2      = (const float*)d_in[3];
  const float* b2      = (const float*)d_in[4];
  const float* gateW   = (const float*)d_in[5];
  const float* sharedW = (const float*)d_in[6];
  const float* sharedB = (const float*)d_in[7];
  const float* gamma   = (const float*)d_in[8];
  const float* beta    = (const float*)d_in[9];
  float* out = (float*)d_out;

  char* ws = (char*)d_ws;
  size_t off = 0;
  auto alloc = [&](size_t bytes) -> void* {
    void* p = ws + off;
    off += (bytes + 255) & ~(size_t)255;
    return p;
  };
  int*   counts = (int*)alloc(NEXP * 4);
  int*   offs   = (int*)alloc((NEXP + 1) * 4);
  int*   cursor = (int*)alloc(NEXP * 4);
  int*   topk_e = (int*)alloc((size_t)N_TOK * 2 * 4);
  float* topk_w = (float*)alloc((size_t)N_TOK * 2 * 4);
  int*   rowmap = (int*)alloc((size_t)N_TOK * 2 * 4);
  unsigned short* xbf  = (unsigned short*)alloc((size_t)N_TOK * DIM * 2);
  unsigned short* W1t  = (unsigned short*)alloc((size_t)NEXP * HID * DIM * 2);
  unsigned short* W2t  = (unsigned short*)alloc((size_t)NEXP * DOUT * HID * 2);
  unsigned short* sWt  = (unsigned short*)alloc((size_t)DOUT * DIM * 2);
  unsigned short* hbuf = (unsigned short*)alloc((size_t)N_TOK * 2 * HID * 2);
  float* accb = (float*)alloc((size_t)N_TOK * DOUT * 4);
  if (off > ws_size) return;  // workspace too small -> fail validation loudly

  init_kernel<<<1, 64, 0, stream>>>(counts);
  cast_x_kernel<<<N_TOK * DIM / 1024, 256, 0, stream>>>(x, xbf);
  transpose_cast_kernel<<<dim3(HID / 32, DIM / 32, NEXP), dim3(32, 8), 0, stream>>>(W1, W1t, DIM, HID);
  transpose_cast_kernel<<<dim3(DOUT / 32, HID / 32, NEXP), dim3(32, 8), 0, stream>>>(W2, W2t, HID, DOUT);
  transpose_cast_kernel<<<dim3(DOUT / 32, DIM / 32, 1), dim3(32, 8), 0, stream>>>(sharedW, sWt, DIM, DOUT);
  gate_kernel<<<N_TOK / 4, 256, 0, stream>>>(x, gateW, topk_e, topk_w, counts);
  offsets_kernel<<<1, 64, 0, stream>>>(counts, offs, cursor);
  scatter_kernel<<<N_TOK / 256, 256, 0, stream>>>(topk_e, cursor, rowmap);

  // expert GEMM1: h = gelu(x @ W1 + b1), gathered rows, grid self-limits
  gemm_mfma<0><<<NEXP * 64 * (HID / 128), 256, 0, stream>>>(
      xbf, W1t, b1, hbuf, nullptr, rowmap, offs, topk_w, DIM, HID, 0, 64, HID / 128);
  // shared GEMM: accb = 0.5*gelu(x @ sharedW + sb)  (initializes accb)
  gemm_mfma<2><<<64 * (DOUT / 128), 256, 0, stream>>>(
      xbf, sWt, sharedB, nullptr, accb, nullptr, nullptr, nullptr, DIM, DOUT, N_TOK, 64, DOUT / 128);
  // expert GEMM2: accb += w * (h @ W2 + b2)
  gemm_mfma<1><<<NEXP * 64 * (DOUT / 128), 256, 0, stream>>>(
      hbuf, W2t, b2, nullptr, accb, rowmap, offs, topk_w, HID, DOUT, 0, 64, DOUT / 128);
  // LayerNorm -> out
  ln_kernel<<<N_TOK, 256, 0, stream>>>(accb, gamma, beta, out);
}